// Round 10
// baseline (8121.123 us; speedup 1.0000x reference)
//
#include <hip/hip_runtime.h>

// VQ-VAE EMA codebook update for MI355X (gfx950) — bf16-MFMA filter + fp32 rescore,
// with the gather/scatter epilogue FUSED into the rescore loop (z-row stays in
// wave registers; saves a full 512 MB z re-read).
// N=262144 rows, K=512 codes, D=512 dims, fp32 in/out.
//
// Outputs (flat concat): z_q_x_bar[N*D], z_q_x[N*D], perplexity[1],
// usage_total[1], new_codebook[K*D], new_code_sum[K*D], new_code_count[K].
//
// ws layout: cs_acc[K*D] f32, cc_acc[K] f32, cnh[K] f32, cb_bf[K*D] bf16.
//
// Exactness: bf16 dot error |s~ - s| <= ~1.8 near worst case (capture failure
// would need a >30-sigma |z.c| excursion). Candidate window eps=8.0 on
// half-dist t = |c|^2/2 - s captures the fp32 argmin with >2x margin
// (needs 2E ~ 3.6). Rows with exactly one candidate take it directly
// (argmin over a capturing singleton). Rows with >CAP candidates fall back
// to a full fp32 scan of all K codes.

#define DDIM 512
#define KCODES 512
#define BMR 64            // rows per block
#define BKC 64            // k-chunk (2 MFMA k-steps of 32)
#define NCHUNK (DDIM / BKC)
#define EPS_CAND 8.0f
#define CAP 12            // candidate list capacity per row

typedef short s16x8 __attribute__((ext_vector_type(8)));   // 8 bf16 (4 VGPRs)
typedef float f32x4 __attribute__((ext_vector_type(4)));

static __device__ __forceinline__ float4 ld4(const float* p) {
    return *reinterpret_cast<const float4*>(p);
}
static __device__ __forceinline__ short f2bf(float f) {     // RTNE float->bf16 bits
    unsigned u = __float_as_uint(f);
    return (short)((u + 0x7FFFu + ((u >> 16) & 1u)) >> 16);
}
static __device__ __forceinline__ s16x8 pack8(float4 a, float4 b) {
    s16x8 r;
    r[0] = f2bf(a.x); r[1] = f2bf(a.y); r[2] = f2bf(a.z); r[3] = f2bf(a.w);
    r[4] = f2bf(b.x); r[5] = f2bf(b.y); r[6] = f2bf(b.z); r[7] = f2bf(b.w);
    return r;
}

// ------------------------------------------------------------------ prep ----
// Per code row: cnh = ||c||^2 / 2 (fp32), and bf16 conversion of the row.
__global__ void prep_kernel(const float* __restrict__ cb,
                            float* __restrict__ cnh,
                            short* __restrict__ cb_bf) {
    const int k = blockIdx.x, l = threadIdx.x;   // 64 lanes, 8 elems each
    const float* row = cb + (size_t)k * DDIM + l * 8;
    float4 a = ld4(row), b = ld4(row + 4);
    *reinterpret_cast<s16x8*>(cb_bf + (size_t)k * DDIM + l * 8) = pack8(a, b);
    float s = a.x*a.x + a.y*a.y + a.z*a.z + a.w*a.w
            + b.x*b.x + b.y*b.y + b.z*b.z + b.w*b.w;
#pragma unroll
    for (int m = 32; m; m >>= 1) s += __shfl_xor(s, m, 64);
    if (l == 0) cnh[k] = s * 0.5f;
}

// ------------------------------------------------------------------ main ----
// 256 thr = 4 waves. Wave wv: 64 rows x codes [128wv,128wv+128). acc[4][8] f32x4.
// LDS tiles XOR-swizzled: physical slot = logical_khalf ^ (row&7) (16B slots);
// all writes linear slot-major (conflict-free), sources pre-permuted
// (both-sides-or-neither rule); swizzled reads cover all 8 bank quads per
// 8-lane phase (<=2-way, free per m136).
__global__ __launch_bounds__(256, 2) void vq_main(
    const float* __restrict__ z, const float* __restrict__ cb,
    const short* __restrict__ cb_bf, const float* __restrict__ cnh_g,
    float* __restrict__ out_bar, float* __restrict__ out_q,
    float* __restrict__ cs_acc, float* __restrict__ cc_acc)
{
    __shared__ __align__(16) short Az[BMR * BKC];       // 8 KB
    __shared__ __align__(16) short Bc[KCODES * BKC];    // 64 KB
    __shared__ float cnhs[KCODES];
    __shared__ float wmin[4][BMR];
    __shared__ float bmin[BMR];
    __shared__ int   cnt[BMR];
    __shared__ int   cand[BMR][CAP];

    const int tid = threadIdx.x;
    const int wv = tid >> 6;       // wave 0..3
    const int l  = tid & 63;       // lane
    const int n0 = blockIdx.x * BMR;

    for (int i = tid; i < KCODES; i += 256) cnhs[i] = cnh_g[i];
    if (tid < BMR) cnt[tid] = 0;

    f32x4 acc[4][8];
#pragma unroll
    for (int m = 0; m < 4; ++m)
#pragma unroll
        for (int n = 0; n < 8; ++n) { acc[m][n][0]=0.f; acc[m][n][1]=0.f; acc[m][n][2]=0.f; acc[m][n][3]=0.f; }

#pragma unroll 1
    for (int ch = 0; ch < NCHUNK; ++ch) {
        const int dc = ch * BKC;
        // ---- stage Az: linear slot-major LDS writes, source k-half pre-permuted
#pragma unroll
        for (int i = 0; i < 2; ++i) {
            int sidx = i * 256 + tid;          // 0..511 (16B slots)
            int row = sidx >> 3, slot = sidx & 7;
            int h = slot ^ (row & 7);
            const float* src = z + (size_t)(n0 + row) * DDIM + dc + h * 8;
            *reinterpret_cast<s16x8*>(&Az[sidx * 8]) = pack8(ld4(src), ld4(src + 4));
        }
        // ---- stage Bc: linear slot-major LDS writes, source k-half pre-permuted
#pragma unroll
        for (int i = 0; i < 16; ++i) {
            int slot = i * 256 + tid;          // 0..4095 (16B units)
            int code = slot >> 3, q = slot & 7;
            int hh = q ^ (code & 7);
            *reinterpret_cast<s16x8*>(&Bc[slot * 8]) =
                *reinterpret_cast<const s16x8*>(cb_bf + (size_t)code * DDIM + dc + hh * 8);
        }
        __syncthreads();
        // ---- compute: 2 k-steps of 32 ----
#pragma unroll
        for (int ks = 0; ks < 2; ++ks) {
            const int hh = ks * 4 + (l >> 4);
            s16x8 aF[4];
#pragma unroll
            for (int m = 0; m < 4; ++m) {
                int row = m * 16 + (l & 15);
                int slot = hh ^ (row & 7);
                aF[m] = *reinterpret_cast<const s16x8*>(&Az[row * BKC + slot * 8]);
            }
#pragma unroll
            for (int n = 0; n < 8; ++n) {
                int code = wv * 128 + n * 16 + (l & 15);
                int slot = hh ^ (code & 7);
                s16x8 bF = *reinterpret_cast<const s16x8*>(&Bc[code * BKC + slot * 8]);
#pragma unroll
                for (int m = 0; m < 4; ++m)
                    acc[m][n] = __builtin_amdgcn_mfma_f32_16x16x32_bf16(aF[m], bF, acc[m][n], 0, 0, 0);
            }
        }
        __syncthreads();
    }

    // ---- per-lane code half-norms for its 8 fragment columns ----
    float cnr[8];
#pragma unroll
    for (int n = 0; n < 8; ++n) cnr[n] = cnhs[wv * 128 + n * 16 + (l & 15)];

    // ---- per-row min of t = cnh - s over this wave's 128 codes ----
    float pm[4][4];
#pragma unroll
    for (int m = 0; m < 4; ++m)
#pragma unroll
        for (int r = 0; r < 4; ++r) {
            float v = 3.4e38f;
#pragma unroll
            for (int n = 0; n < 8; ++n) v = fminf(v, cnr[n] - acc[m][n][r]);
            pm[m][r] = v;
        }
#pragma unroll
    for (int msk = 1; msk < 16; msk <<= 1)
#pragma unroll
        for (int m = 0; m < 4; ++m)
#pragma unroll
            for (int r = 0; r < 4; ++r)
                pm[m][r] = fminf(pm[m][r], __shfl_xor(pm[m][r], msk, 64));
    if ((l & 15) == 0) {
#pragma unroll
        for (int m = 0; m < 4; ++m)
#pragma unroll
            for (int r = 0; r < 4; ++r)
                wmin[wv][m * 16 + (l >> 4) * 4 + r] = pm[m][r];
    }
    __syncthreads();
    if (tid < BMR)
        bmin[tid] = fminf(fminf(wmin[0][tid], wmin[1][tid]), fminf(wmin[2][tid], wmin[3][tid]));
    __syncthreads();

    // ---- candidate scan: t <= rowmin + EPS (provably captures fp32 argmin) ----
    float rm[4][4];
#pragma unroll
    for (int m = 0; m < 4; ++m)
#pragma unroll
        for (int r = 0; r < 4; ++r) rm[m][r] = bmin[m * 16 + (l >> 4) * 4 + r];
#pragma unroll
    for (int m = 0; m < 4; ++m)
#pragma unroll
        for (int n = 0; n < 8; ++n)
#pragma unroll
            for (int r = 0; r < 4; ++r) {
                float t = cnr[n] - acc[m][n][r];
                if (t <= rm[m][r] + EPS_CAND) {
                    int row = m * 16 + (l >> 4) * 4 + r;
                    int code = wv * 128 + n * 16 + (l & 15);
                    int p = atomicAdd(&cnt[row], 1);
                    if (p < CAP) cand[row][p] = code;
                }
            }
    __syncthreads();

    // ---- fused rescore + epilogue: wave wv owns rows wv, wv+4, ...
    //      The wave holds the full fp32 z-row in registers (lane l: elems l*8..+7),
    //      so gather (z_q, z_q_bar) and scatter (segment_sum) run here — no
    //      separate epilogue pass, z read exactly once post-staging.
#pragma unroll 1
    for (int j = 0; j < 16; ++j) {
        int r = j * 4 + wv;
        int nc = cnt[r];
        const float* zr = z + (size_t)(n0 + r) * DDIM + l * 8;
        float zv[8];
#pragma unroll
        for (int e = 0; e < 8; ++e) zv[e] = zr[e];

        int bc = 0;
        if (nc == 1) {
            bc = cand[r][0];           // capturing singleton == argmin
        } else {
            float bt = 3.4e38f;
            if (nc > CAP) {
                // rare exact fallback: all codes
#pragma unroll 1
                for (int c = 0; c < KCODES; ++c) {
                    const float* cr = cb + (size_t)c * DDIM + l * 8;
                    float s = 0.f;
#pragma unroll
                    for (int e = 0; e < 8; ++e) s = fmaf(zv[e], cr[e], s);
#pragma unroll
                    for (int msk = 1; msk < 64; msk <<= 1) s += __shfl_xor(s, msk, 64);
                    float t = cnhs[c] - s;
                    if (t < bt || (t == bt && c < bc)) { bt = t; bc = c; }
                }
            } else {
#pragma unroll 1
                for (int ci = 0; ci < nc; ++ci) {
                    int c = cand[r][ci];
                    const float* cr = cb + (size_t)c * DDIM + l * 8;
                    float s = 0.f;
#pragma unroll
                    for (int e = 0; e < 8; ++e) s = fmaf(zv[e], cr[e], s);
#pragma unroll
                    for (int msk = 1; msk < 64; msk <<= 1) s += __shfl_xor(s, msk, 64);
                    float t = cnhs[c] - s;
                    if (t < bt || (t == bt && c < bc)) { bt = t; bc = c; }
                }
            }
        }
        if (l == 0) atomicAdd(cc_acc + bc, 1.0f);

        // gather + outputs + scatter, all from registers
        const float* qr = cb + (size_t)bc * DDIM + l * 8;
        float qv[8], bar[8];
#pragma unroll
        for (int e = 0; e < 8; ++e) {
            qv[e]  = qr[e];
            bar[e] = zv[e] + (qv[e] - zv[e]);
        }
        size_t o = (size_t)(n0 + r) * DDIM + l * 8;
        *reinterpret_cast<float4*>(out_q + o)       = *reinterpret_cast<float4*>(&qv[0]);
        *reinterpret_cast<float4*>(out_q + o + 4)   = *reinterpret_cast<float4*>(&qv[4]);
        *reinterpret_cast<float4*>(out_bar + o)     = *reinterpret_cast<float4*>(&bar[0]);
        *reinterpret_cast<float4*>(out_bar + o + 4) = *reinterpret_cast<float4*>(&bar[4]);
        float* csrow = cs_acc + (size_t)bc * DDIM + l * 8;
#pragma unroll
        for (int e = 0; e < 8; ++e) atomicAdd(csrow + e, zv[e]);
    }
}

// ---------------------------------------------------------- finalize KD ----
__global__ void finalize_kd(const float* __restrict__ code_sum,
                            const float* __restrict__ code_count,
                            const float* __restrict__ cs_acc,
                            const float* __restrict__ cc_acc,
                            const float* __restrict__ z,
                            float* __restrict__ out_cb,
                            float* __restrict__ out_sum)
{
    const float OM = 0.01f;
    int idx4 = blockIdx.x * 256 + threadIdx.x;
    int k  = idx4 >> 7;
    int d4 = idx4 & 127;
    size_t o = (size_t)k * DDIM + d4 * 4;
    float4 so = ld4(code_sum + o);
    float4 cs = ld4(cs_acc + o);
    float4 ns;
    ns.x = __fadd_rn(__fmul_rn(0.99f, so.x), __fmul_rn(OM, cs.x));
    ns.y = __fadd_rn(__fmul_rn(0.99f, so.y), __fmul_rn(OM, cs.y));
    ns.z = __fadd_rn(__fmul_rn(0.99f, so.z), __fmul_rn(OM, cs.z));
    ns.w = __fadd_rn(__fmul_rn(0.99f, so.w), __fmul_rn(OM, cs.w));
    float cnt = __fadd_rn(__fmul_rn(0.99f, code_count[k]), __fmul_rn(OM, cc_acc[k]));
    bool usage = (cnt >= 1.0f);
    float4 rnd = ld4(z + o);
    float4 ocb;
    ocb.x = usage ? (ns.x / cnt) : rnd.x;
    ocb.y = usage ? (ns.y / cnt) : rnd.y;
    ocb.z = usage ? (ns.z / cnt) : rnd.z;
    ocb.w = usage ? (ns.w / cnt) : rnd.w;
    *reinterpret_cast<float4*>(out_sum + o) = ns;
    *reinterpret_cast<float4*>(out_cb + o) = ocb;
}

// ----------------------------------------------------------- finalize K ----
__global__ void finalize_k(const float* __restrict__ code_count,
                           const float* __restrict__ cc_acc,
                           float* __restrict__ out_count,
                           float* __restrict__ out_perp,
                           float* __restrict__ out_usage)
{
    const float OM = 0.01f;
    const int lane = threadIdx.x;
    float cc[8], cnt[8];
    float ssum = 0.f;
#pragma unroll
    for (int i = 0; i < 8; ++i) {
        int k = lane + i * 64;
        cc[i]  = cc_acc[k];
        cnt[i] = __fadd_rn(__fmul_rn(0.99f, code_count[k]), __fmul_rn(OM, cc[i]));
        out_count[k] = cnt[i];
        ssum += cc[i];
    }
#pragma unroll
    for (int m = 32; m; m >>= 1) ssum += __shfl_xor(ssum, m, 64);
    float ent = 0.f, us = 0.f;
#pragma unroll
    for (int i = 0; i < 8; ++i) {
        float p = cc[i] / ssum;
        ent += p * logf(p + 1e-7f);
        us += (cnt[i] >= 1.0f) ? 1.f : 0.f;
    }
#pragma unroll
    for (int m = 32; m; m >>= 1) {
        ent += __shfl_xor(ent, m, 64);
        us  += __shfl_xor(us, m, 64);
    }
    if (lane == 0) {
        out_perp[0]  = expf(-ent);
        out_usage[0] = us;
    }
}

// --------------------------------------------------------------- launch ----
extern "C" void kernel_launch(void* const* d_in, const int* in_sizes, int n_in,
                              void* d_out, int out_size, void* d_ws, size_t ws_size,
                              hipStream_t stream) {
    (void)n_in; (void)out_size; (void)ws_size;
    const float* z          = (const float*)d_in[0];
    const float* cb         = (const float*)d_in[1];
    const float* code_sum   = (const float*)d_in[2];
    const float* code_count = (const float*)d_in[3];

    const int N = in_sizes[0] / DDIM;   // 262144
    const int K = in_sizes[3];          // 512

    float* out       = (float*)d_out;
    float* out_bar   = out;
    float* out_q     = out + (size_t)N * DDIM;
    float* out_perp  = out + 2ull * N * DDIM;
    float* out_usage = out_perp + 1;
    float* out_cb    = out_usage + 1;
    float* out_sum   = out_cb + (size_t)K * DDIM;
    float* out_count = out_sum + (size_t)K * DDIM;

    float* cs_acc = (float*)d_ws;
    float* cc_acc = cs_acc + (size_t)K * DDIM;
    float* cnh    = cc_acc + K;
    short* cb_bf  = (short*)(cnh + K);

    hipMemsetAsync(d_ws, 0, ((size_t)K * DDIM + K) * sizeof(float), stream);
    prep_kernel<<<K, 64, 0, stream>>>(cb, cnh, cb_bf);
    vq_main<<<N / BMR, 256, 0, stream>>>(z, cb, cb_bf, cnh, out_bar, out_q, cs_acc, cc_acc);
    finalize_kd<<<(K * DDIM / 4) / 256, 256, 0, stream>>>(code_sum, code_count, cs_acc,
                                                          cc_acc, z, out_cb, out_sum);
    finalize_k<<<1, 64, 0, stream>>>(code_count, cc_acc, out_count, out_perp, out_usage);
}